// Round 4
// baseline (2441444.922 us; speedup 1.0000x reference)
//
#include <hip/hip_runtime.h>
#include <math.h>

#define B_  32
#define S_  512
#define H_  1024
#define G3_ 3072
#define SENT32 0x7F7F7F7Fu   // bf16 0x7F7F ~ 3.39e38; |h|<1 so unreachable

typedef __attribute__((ext_vector_type(8))) short bf16x8;   // 8 bf16 in 4 VGPRs
typedef __attribute__((ext_vector_type(4))) float f32x4;
typedef __attribute__((ext_vector_type(4))) unsigned int u32x4;

__device__ __forceinline__ unsigned short f2bf(float f) {
  unsigned int u = __float_as_uint(f);
  u = (u + 0x7FFFu + ((u >> 16) & 1u)) >> 16;   // RNE
  return (unsigned short)u;
}

// 16B load, bypass L1, HIT shared per-XCD L2 (sc0 only) -- coherent for
// producer/consumer blocks resident on the SAME XCD.
__device__ __forceinline__ u32x4 ld_b128_sc0(const unsigned short* p) {
  u32x4 r;
  asm volatile("global_load_dwordx4 %0, %1, off sc0" : "=v"(r) : "v"(p));
  return r;   // NOT ready until s_waitcnt vmcnt(0) -- tied through below
}
__device__ __forceinline__ void st_b32_sc0(unsigned short* p, unsigned int v) {
  asm volatile("global_store_dword %0, %1, off sc0" :: "v"(p), "v"(v) : "memory");
}

__global__ void cast_f32_bf16(const float* __restrict__ in, unsigned short* __restrict__ out, int n) {
  int i = blockIdx.x * 256 + threadIdx.x;
  if (i < n) out[i] = f2bf(in[i]);
}

// x (B,S,512) fp32 -> xtm (S,B,512) bf16
__global__ void cast_transpose_x(const float* __restrict__ x, unsigned short* __restrict__ xtm) {
  int s = blockIdx.x & 511, b = blockIdx.x >> 9;   // grid 16384
  int k = threadIdx.x * 4;                          // 128 threads
  float4 v = *(const float4*)(x + ((size_t)b * S_ + s) * 512 + k);
  ushort4 o = { f2bf(v.x), f2bf(v.y), f2bf(v.z), f2bf(v.w) };
  *(ushort4*)(xtm + ((size_t)s * B_ + b) * 512 + k) = o;
}

// ---------------- big GEMM (verified; used for final projection) ----------------
template<int APERM, int CPERM, typename CT>
__global__ __launch_bounds__(256)
void gemm_bf16(const unsigned short* __restrict__ A, const unsigned short* __restrict__ W,
               const float* __restrict__ bias, CT* __restrict__ C, int M, int N, int K) {
  __shared__ __align__(16) unsigned short As[128 * 40];
  __shared__ __align__(16) unsigned short Ws[128 * 40];
  const int tid   = threadIdx.x;
  const int mBase = blockIdx.y * 128;
  const int nBase = blockIdx.x * 128;
  const int lane  = tid & 63;
  const int w     = tid >> 6;
  const int wm    = (w & 1) * 64;
  const int wn    = (w >> 1) * 64;
  const int r16   = lane & 15;
  const int q     = lane >> 4;

  f32x4 acc[4][4];
  for (int i = 0; i < 4; ++i)
    for (int j = 0; j < 4; ++j)
      for (int t = 0; t < 4; ++t) acc[i][j][t] = 0.f;

  const int r0  = tid >> 2;
  const int kk0 = (tid & 3) * 8;

  for (int k0 = 0; k0 < K; k0 += 32) {
    {
      int r = r0;
      size_t ar = APERM ? ((size_t)((mBase + r) & 31) * S_ + (size_t)((mBase + r) >> 5)) : (size_t)(mBase + r);
      *(uint4*)&As[r * 40 + kk0] = *(const uint4*)(A + ar * K + k0 + kk0);
      int r2 = r + 64;
      size_t ar2 = APERM ? ((size_t)((mBase + r2) & 31) * S_ + (size_t)((mBase + r2) >> 5)) : (size_t)(mBase + r2);
      *(uint4*)&As[r2 * 40 + kk0] = *(const uint4*)(A + ar2 * K + k0 + kk0);
      *(uint4*)&Ws[r * 40 + kk0]  = *(const uint4*)(W + (size_t)(nBase + r)  * K + k0 + kk0);
      *(uint4*)&Ws[r2 * 40 + kk0] = *(const uint4*)(W + (size_t)(nBase + r2) * K + k0 + kk0);
    }
    __syncthreads();
    bf16x8 af[4], bfr[4];
#pragma unroll
    for (int i = 0; i < 4; ++i) af[i]  = *(const bf16x8*)&As[(wm + i * 16 + r16) * 40 + q * 8];
#pragma unroll
    for (int j = 0; j < 4; ++j) bfr[j] = *(const bf16x8*)&Ws[(wn + j * 16 + r16) * 40 + q * 8];
#pragma unroll
    for (int i = 0; i < 4; ++i)
#pragma unroll
      for (int j = 0; j < 4; ++j)
        acc[i][j] = __builtin_amdgcn_mfma_f32_16x16x32_bf16(af[i], bfr[j], acc[i][j], 0, 0, 0);
    __syncthreads();
  }

#pragma unroll
  for (int i = 0; i < 4; ++i)
#pragma unroll
    for (int j = 0; j < 4; ++j)
#pragma unroll
      for (int t = 0; t < 4; ++t) {
        int m = mBase + wm + i * 16 + q * 4 + t;
        int n = nBase + wn + j * 16 + r16;
        float v = acc[i][j][t] + bias[n];
        size_t crow = CPERM ? ((size_t)(m & 31) * S_ + (size_t)(m >> 5)) : (size_t)m;
        if constexpr (sizeof(CT) == 4) C[crow * N + n] = v;
        else                           C[crow * N + n] = f2bf(v);
      }
}

// ---------------- fused 2-layer persistent GRU, XCD-local h-exchange ----------------
// Grid 512 x 512thr. Role = blockIdx%8 (== XCD under round-robin dispatch):
// role 0 -> layer-0 block (bidx = blockIdx/8, 0..63), role 1 -> layer-1, else exit.
// So each layer's 64 blocks land 2/CU on ONE XCD and share a coherent L2.
// Within-layer h[t-1] exchange then uses sc0-only stores/loads (L2, ~10x lower
// latency than MALL). Safety: each block publishes HW_REG_XCC_ID; the fast path
// engages only if all 64 members of the layer verify same-XCD, else falls back
// to agent-scope atomics (MALL; correct, previous-round speed).
// Cross-layer y0 traffic stays agent-scope/MALL: it is a constant pipeline
// offset for L1, not a per-step cost.

__global__ __launch_bounds__(512, 4)
void gru_fused(const unsigned short* __restrict__ wih0, const unsigned short* __restrict__ whh0,
               const float* __restrict__ b0,
               const unsigned short* __restrict__ wih1, const unsigned short* __restrict__ whh1,
               const float* __restrict__ b1,
               const unsigned short* __restrict__ xtm, const unsigned short* __restrict__ zerosB,
               unsigned short* __restrict__ y0, unsigned short* __restrict__ y1,
               unsigned short* __restrict__ hb0, unsigned short* __restrict__ hb1,
               unsigned int* __restrict__ pub,
               float* __restrict__ hlast0, float* __restrict__ hlast1) {
  __shared__ __align__(16) float part[8 * 2 * 3 * 64 * 4];   // 48 KB [w][m][g][lane][reg]
  __shared__ int sFast;
  const int role = blockIdx.x & 7;
  if (role >= 2) return;
  const bool L1  = (role == 1);
  const int bidx = blockIdx.x >> 3;       // 0..63
  const int j0   = bidx * 16;

  const int tid  = threadIdx.x;
  const int lane = tid & 63;
  const int w    = tid >> 6;          // 0..7
  const int r16  = lane & 15;
  const int q    = lane >> 4;
  const bool hiw = w >= 4;

  // ---- XCD same-placement check (one-time) ----
  unsigned xcc;
  asm volatile("s_getreg_b32 %0, hwreg(HW_REG_XCC_ID)" : "=s"(xcc));
  if (tid == 0)
    __hip_atomic_store(&pub[(L1 ? 64 : 0) + bidx], xcc | 0x100u,
                       __ATOMIC_RELAXED, __HIP_MEMORY_SCOPE_AGENT);
  if (w == 0) {
    unsigned mine = xcc | 0x100u;
    unsigned v = 0;
    for (int sp = 0; sp < 200000; ++sp) {
      v = __hip_atomic_load(&pub[(L1 ? 64 : 0) + lane],
                            __ATOMIC_RELAXED, __HIP_MEMORY_SCOPE_AGENT);
      if (__all(v != 0)) break;
      __builtin_amdgcn_s_sleep(8);
    }
    int same = __all(v == mine);
    if (lane == 0) sFast = same;
  }
  __syncthreads();
  const bool fastH = (sFast != 0);

  // per-wave operand plan
  const unsigned short* Wsrc;
  int wstride, kbase, ncha;
  if (!L1) {
    if (!hiw) { Wsrc = wih0; wstride = 512;  kbase = w * 128;       ncha = 4; }
    else      { Wsrc = whh0; wstride = 1024; kbase = (w - 4) * 256; ncha = 8; }
  } else {
    if (!hiw) { Wsrc = wih1; wstride = 1024; kbase = w * 256;       ncha = 8; }
    else      { Wsrc = whh1; wstride = 1024; kbase = (w - 4) * 256; ncha = 8; }
  }

  // B-frags -> registers, once
  bf16x8 bw[3][8];
#pragma unroll
  for (int g = 0; g < 3; ++g)
#pragma unroll
    for (int c = 0; c < 8; ++c)
      if (c < ncha)
        bw[g][c] = *(const bf16x8*)(Wsrc + (size_t)(g * H_ + j0 + r16) * wstride + kbase + c * 32 + q * 8);

  const float* bias = L1 ? b1 : b0;
  float br[2], bz[2], bn[2], phv[2] = {0.f, 0.f};
  if (tid < 256) {
    int jj = j0 + (tid & 7) * 2;
#pragma unroll
    for (int e = 0; e < 2; ++e) {
      br[e] = bias[jj + e]; bz[e] = bias[H_ + jj + e]; bn[e] = bias[2 * H_ + jj + e];
    }
  }

  unsigned short* ybuf  = L1 ? y1  : y0;
  unsigned short* hbuf  = L1 ? hb1 : hb0;
  float*          hlast = L1 ? hlast1 : hlast0;

  for (int t = 0; t < S_; ++t) {
    // ---- A-frags ----
    const unsigned short* Asrc;
    int astride; bool plainA;
    bool fastPoll = false;
    if (!hiw) {
      if (!L1) { Asrc = xtm + (size_t)t * B_ * 512; astride = 512;  plainA = true; }
      else     { Asrc = y0  + (size_t)t * B_ * H_;  astride = 1024; plainA = false; }
    } else {
      astride = 1024; plainA = (t == 0);
      if (t == 0)      Asrc = zerosB;
      else if (fastH) { Asrc = hbuf + (size_t)(t - 1) * B_ * H_; fastPoll = true; }
      else             Asrc = ybuf + (size_t)(t - 1) * B_ * H_;
    }
    union AU { unsigned long long qq[2]; unsigned int dd[4]; u32x4 u4; bf16x8 v; };
    AU a0[8], a1[8];
    const unsigned short* ap0 = Asrc + (size_t)r16 * astride + kbase + q * 8;
    const unsigned short* ap1 = ap0 + 16 * astride;
    if (plainA) {
#pragma unroll
      for (int c = 0; c < 8; ++c) if (c < ncha) {
        a0[c].v = *(const bf16x8*)(ap0 + c * 32);
        a1[c].v = *(const bf16x8*)(ap1 + c * 32);
      }
    } else if (fastPoll) {
      // h-waves always have ncha==8: poll via sc0 loads hitting the shared XCD L2
      int spins = 0;
      for (;;) {
#pragma unroll
        for (int c = 0; c < 8; ++c) {
          a0[c].u4 = ld_b128_sc0(ap0 + c * 32);
          a1[c].u4 = ld_b128_sc0(ap1 + c * 32);
        }
        asm volatile("s_waitcnt vmcnt(0)"
          : "+v"(a0[0].u4), "+v"(a0[1].u4), "+v"(a0[2].u4), "+v"(a0[3].u4),
            "+v"(a0[4].u4), "+v"(a0[5].u4), "+v"(a0[6].u4), "+v"(a0[7].u4),
            "+v"(a1[0].u4), "+v"(a1[1].u4), "+v"(a1[2].u4), "+v"(a1[3].u4),
            "+v"(a1[4].u4), "+v"(a1[5].u4), "+v"(a1[6].u4), "+v"(a1[7].u4)
          :: "memory");
        int ok = 1;
#pragma unroll
        for (int c = 0; c < 8; ++c)
#pragma unroll
          for (int d = 0; d < 4; ++d)
            ok &= (a0[c].dd[d] != SENT32) & (a1[c].dd[d] != SENT32);
        if (__all(ok)) break;
        if (++spins > (1 << 20)) break;    // hang-safety only
        if (spins > 4) __builtin_amdgcn_s_sleep(1);
      }
    } else {
      // agent-scope (MALL) poll: L1 x-waves on y0[t]; h-waves in fallback mode
      int spins = 0;
      for (;;) {
        int ok = 1;
#pragma unroll
        for (int c = 0; c < 8; ++c) if (c < ncha) {
          unsigned long long* p0 = (unsigned long long*)(ap0 + c * 32);
          unsigned long long* p1 = (unsigned long long*)(ap1 + c * 32);
          a0[c].qq[0] = __hip_atomic_load(p0,     __ATOMIC_RELAXED, __HIP_MEMORY_SCOPE_AGENT);
          a0[c].qq[1] = __hip_atomic_load(p0 + 1, __ATOMIC_RELAXED, __HIP_MEMORY_SCOPE_AGENT);
          a1[c].qq[0] = __hip_atomic_load(p1,     __ATOMIC_RELAXED, __HIP_MEMORY_SCOPE_AGENT);
          a1[c].qq[1] = __hip_atomic_load(p1 + 1, __ATOMIC_RELAXED, __HIP_MEMORY_SCOPE_AGENT);
        }
#pragma unroll
        for (int c = 0; c < 8; ++c) if (c < ncha) {
#pragma unroll
          for (int d = 0; d < 4; ++d)
            ok &= (a0[c].dd[d] != SENT32) & (a1[c].dd[d] != SENT32);
        }
        if (__all(ok)) break;
        if (++spins > (1 << 20)) break;    // hang-safety only
        __builtin_amdgcn_s_sleep(1);
      }
    }

    f32x4 acc[2][3];
#pragma unroll
    for (int m = 0; m < 2; ++m)
#pragma unroll
      for (int g = 0; g < 3; ++g)
#pragma unroll
        for (int u = 0; u < 4; ++u) acc[m][g][u] = 0.f;

#pragma unroll
    for (int c = 0; c < 8; ++c) if (c < ncha)
#pragma unroll
      for (int g = 0; g < 3; ++g) {
        acc[0][g] = __builtin_amdgcn_mfma_f32_16x16x32_bf16(a0[c].v, bw[g][c], acc[0][g], 0, 0, 0);
        acc[1][g] = __builtin_amdgcn_mfma_f32_16x16x32_bf16(a1[c].v, bw[g][c], acc[1][g], 0, 0, 0);
      }

#pragma unroll
    for (int m = 0; m < 2; ++m)
#pragma unroll
      for (int g = 0; g < 3; ++g)
        *(f32x4*)&part[(((w * 2 + m) * 3 + g) * 64 + lane) * 4] = acc[m][g];
    __syncthreads();

    // ---- epilogue: 256 threads x 2 outputs; stores are the signal ----
    if (tid < 256) {
      unsigned short* yt = ybuf + (size_t)t * (B_ * H_);
      unsigned short* ht = hbuf + (size_t)t * (B_ * H_);
      int b = tid >> 3, jp = (tid & 7) * 2;
      float hv2[2];
#pragma unroll
      for (int e = 0; e < 2; ++e) {
        int jj = jp + e;
        float hr = 0.f, hz = 0.f, nx = 0.f, nh = 0.f;
        int m = b >> 4, q2 = (b >> 2) & 3, reg = b & 3;
#pragma unroll
        for (int ww = 0; ww < 8; ++ww) {
          int base = (ww * 2 + m) * 3;
          float vr = part[((base + 0) * 64 + q2 * 16 + jj) * 4 + reg];
          float vz = part[((base + 1) * 64 + q2 * 16 + jj) * 4 + reg];
          float vn = part[((base + 2) * 64 + q2 * 16 + jj) * 4 + reg];
          hr += vr; hz += vz;
          if (ww < 4) nx += vn; else nh += vn;
        }
        float r  = __builtin_amdgcn_rcpf(1.f + __expf(-(hr + br[e])));
        float z  = __builtin_amdgcn_rcpf(1.f + __expf(-(hz + bz[e])));
        float a2 = nx + bn[e] + nh + r * nh;
        float nn = 1.f - 2.f * __builtin_amdgcn_rcpf(__expf(2.f * a2) + 1.f);  // tanh
        float hv = (1.f - z) * nn + z * phv[e];
        phv[e] = hv; hv2[e] = hv;
      }
      unsigned int pk = (unsigned int)f2bf(hv2[0]) | ((unsigned int)f2bf(hv2[1]) << 16);
      if (fastH) st_b32_sc0(ht + (size_t)b * H_ + j0 + jp, pk);   // XCD-local signal
      __hip_atomic_store((unsigned int*)(yt + (size_t)b * H_ + j0 + jp), pk,
                         __ATOMIC_RELAXED, __HIP_MEMORY_SCOPE_AGENT);
      if (t == S_ - 1) {
        hlast[b * H_ + j0 + jp]     = hv2[0];
        hlast[b * H_ + j0 + jp + 1] = hv2[1];
      }
    }
    __syncthreads();   // protect part[]; drains stores (vmcnt) at barrier
  }
}

extern "C" void kernel_launch(void* const* d_in, const int* in_sizes, int n_in,
                              void* d_out, int out_size, void* d_ws, size_t ws_size,
                              hipStream_t stream) {
  const float* x    = (const float*)d_in[0];
  const float* Wih0 = (const float*)d_in[1];
  const float* Whh0 = (const float*)d_in[2];
  const float* b0   = (const float*)d_in[3];
  const float* Wih1 = (const float*)d_in[4];
  const float* Whh1 = (const float*)d_in[5];
  const float* b1   = (const float*)d_in[6];
  const float* Wlin = (const float*)d_in[7];
  const float* blin = (const float*)d_in[8];
  float* out = (float*)d_out;

  char* p = (char*)d_ws;
  size_t off = 0;
  auto alloc = [&](size_t bytes) { void* r = p + off; off += (bytes + 255) & ~(size_t)255; return r; };

  unsigned short* xtm   = (unsigned short*)alloc((size_t)8388608 * 2);   // (S,B,512) bf16
  unsigned short* wih0b = (unsigned short*)alloc((size_t)1572864 * 2);
  unsigned short* whh0b = (unsigned short*)alloc((size_t)3145728 * 2);
  unsigned short* wih1b = (unsigned short*)alloc((size_t)3145728 * 2);
  unsigned short* whh1b = (unsigned short*)alloc((size_t)3145728 * 2);
  unsigned short* wlinb = (unsigned short*)alloc((size_t)524288 * 2);
  unsigned short* y0b   = (unsigned short*)alloc((size_t)16777216 * 2);  // (S,B,H) bf16
  unsigned short* y1b   = (unsigned short*)alloc((size_t)16777216 * 2);
  unsigned short* hb0   = (unsigned short*)alloc((size_t)16777216 * 2);  // XCD-local h exchange
  unsigned short* hb1   = (unsigned short*)alloc((size_t)16777216 * 2);
  unsigned short* zerosB= (unsigned short*)alloc((size_t)B_ * H_ * 2);
  unsigned int*   pub   = (unsigned int*)alloc(512);

  // poison exchange buffers: 0x7F7F bf16 sentinel (unreachable since |h|<1)
  (void)hipMemsetAsync(y0b, 0x7F, (size_t)16777216 * 2, stream);
  (void)hipMemsetAsync(y1b, 0x7F, (size_t)16777216 * 2, stream);
  (void)hipMemsetAsync(hb0, 0x7F, (size_t)16777216 * 2, stream);
  (void)hipMemsetAsync(hb1, 0x7F, (size_t)16777216 * 2, stream);
  (void)hipMemsetAsync(zerosB, 0, (size_t)B_ * H_ * 2, stream);
  (void)hipMemsetAsync(pub, 0, 512, stream);

  auto cast = [&](const float* in, unsigned short* o, int n) {
    cast_f32_bf16<<<n / 256, 256, 0, stream>>>(in, o, n);
  };
  cast_transpose_x<<<16384, 128, 0, stream>>>(x, xtm);
  cast(Wih0, wih0b, 1572864);
  cast(Whh0, whh0b, 3145728);
  cast(Wih1, wih1b, 3145728);
  cast(Whh1, whh1b, 3145728);
  cast(Wlin, wlinb, 524288);

  float* hlast0 = out + 8388608;
  float* hlast1 = out + 8388608 + B_ * H_;

  gru_fused<<<512, 512, 0, stream>>>(wih0b, whh0b, b0, wih1b, whh1b, b1,
                                     xtm, zerosB, y0b, y1b, hb0, hb1, pub,
                                     hlast0, hlast1);

  // final: out = y1 @ Wlin^T + blin, C rows -> (b,s)
  {
    dim3 g(512 / 128, 16384 / 128);
    gemm_bf16<0, 1, float><<<g, 256, 0, stream>>>(y1b, wlinb, blin, out, 16384, 512, 1024);
  }
}

// Round 5
// 3072.560 us; speedup vs baseline: 794.5963x; 794.5963x over previous
//
#include <hip/hip_runtime.h>
#include <math.h>

#define B_  32
#define S_  512
#define H_  1024
#define G3_ 3072
#define SENT32 0x7F7F7F7Fu   // bf16 0x7F7F ~ 3.39e38; |h|<1 so unreachable

typedef __attribute__((ext_vector_type(8))) short bf16x8;   // 8 bf16 in 4 VGPRs
typedef __attribute__((ext_vector_type(4))) float f32x4;
typedef __attribute__((ext_vector_type(4))) unsigned int u32x4;

__device__ __forceinline__ unsigned short f2bf(float f) {
  unsigned int u = __float_as_uint(f);
  u = (u + 0x7FFFu + ((u >> 16) & 1u)) >> 16;   // RNE
  return (unsigned short)u;
}

// 16B load, bypass L1 AND L2 (sc0 sc1) -> MALL, agent-coherent. Issued
// without any waitcnt; caller batches many then waits ONCE.
__device__ __forceinline__ void ld4_mall(const unsigned short* p, u32x4& r) {
  asm volatile("global_load_dwordx4 %0, %1, off sc0 sc1" : "=v"(r) : "v"(p));
}
// 4B store, agent-coherent (MALL). Fire-and-forget; the compiler's vmcnt
// drain before s_barrier covers completion.
__device__ __forceinline__ void st_mall_b32(unsigned short* p, unsigned int v) {
  asm volatile("global_store_dword %0, %1, off sc0 sc1" :: "v"(p), "v"(v) : "memory");
}

__global__ void cast_f32_bf16(const float* __restrict__ in, unsigned short* __restrict__ out, int n) {
  int i = blockIdx.x * 256 + threadIdx.x;
  if (i < n) out[i] = f2bf(in[i]);
}

// x (B,S,512) fp32 -> xtm (S,B,512) bf16
__global__ void cast_transpose_x(const float* __restrict__ x, unsigned short* __restrict__ xtm) {
  int s = blockIdx.x & 511, b = blockIdx.x >> 9;   // grid 16384
  int k = threadIdx.x * 4;                          // 128 threads
  float4 v = *(const float4*)(x + ((size_t)b * S_ + s) * 512 + k);
  ushort4 o = { f2bf(v.x), f2bf(v.y), f2bf(v.z), f2bf(v.w) };
  *(ushort4*)(xtm + ((size_t)s * B_ + b) * 512 + k) = o;
}

// ---------------- big GEMM (verified; used for final projection) ----------------
template<int APERM, int CPERM, typename CT>
__global__ __launch_bounds__(256)
void gemm_bf16(const unsigned short* __restrict__ A, const unsigned short* __restrict__ W,
               const float* __restrict__ bias, CT* __restrict__ C, int M, int N, int K) {
  __shared__ __align__(16) unsigned short As[128 * 40];
  __shared__ __align__(16) unsigned short Ws[128 * 40];
  const int tid   = threadIdx.x;
  const int mBase = blockIdx.y * 128;
  const int nBase = blockIdx.x * 128;
  const int lane  = tid & 63;
  const int w     = tid >> 6;
  const int wm    = (w & 1) * 64;
  const int wn    = (w >> 1) * 64;
  const int r16   = lane & 15;
  const int q     = lane >> 4;

  f32x4 acc[4][4];
  for (int i = 0; i < 4; ++i)
    for (int j = 0; j < 4; ++j)
      for (int t = 0; t < 4; ++t) acc[i][j][t] = 0.f;

  const int r0  = tid >> 2;
  const int kk0 = (tid & 3) * 8;

  for (int k0 = 0; k0 < K; k0 += 32) {
    {
      int r = r0;
      size_t ar = APERM ? ((size_t)((mBase + r) & 31) * S_ + (size_t)((mBase + r) >> 5)) : (size_t)(mBase + r);
      *(uint4*)&As[r * 40 + kk0] = *(const uint4*)(A + ar * K + k0 + kk0);
      int r2 = r + 64;
      size_t ar2 = APERM ? ((size_t)((mBase + r2) & 31) * S_ + (size_t)((mBase + r2) >> 5)) : (size_t)(mBase + r2);
      *(uint4*)&As[r2 * 40 + kk0] = *(const uint4*)(A + ar2 * K + k0 + kk0);
      *(uint4*)&Ws[r * 40 + kk0]  = *(const uint4*)(W + (size_t)(nBase + r)  * K + k0 + kk0);
      *(uint4*)&Ws[r2 * 40 + kk0] = *(const uint4*)(W + (size_t)(nBase + r2) * K + k0 + kk0);
    }
    __syncthreads();
    bf16x8 af[4], bfr[4];
#pragma unroll
    for (int i = 0; i < 4; ++i) af[i]  = *(const bf16x8*)&As[(wm + i * 16 + r16) * 40 + q * 8];
#pragma unroll
    for (int j = 0; j < 4; ++j) bfr[j] = *(const bf16x8*)&Ws[(wn + j * 16 + r16) * 40 + q * 8];
#pragma unroll
    for (int i = 0; i < 4; ++i)
#pragma unroll
      for (int j = 0; j < 4; ++j)
        acc[i][j] = __builtin_amdgcn_mfma_f32_16x16x32_bf16(af[i], bfr[j], acc[i][j], 0, 0, 0);
    __syncthreads();
  }

#pragma unroll
  for (int i = 0; i < 4; ++i)
#pragma unroll
    for (int j = 0; j < 4; ++j)
#pragma unroll
      for (int t = 0; t < 4; ++t) {
        int m = mBase + wm + i * 16 + q * 4 + t;
        int n = nBase + wn + j * 16 + r16;
        float v = acc[i][j][t] + bias[n];
        size_t crow = CPERM ? ((size_t)(m & 31) * S_ + (size_t)(m >> 5)) : (size_t)m;
        if constexpr (sizeof(CT) == 4) C[crow * N + n] = v;
        else                           C[crow * N + n] = f2bf(v);
      }
}

// ---------------- fused 2-layer persistent GRU, data-polled (batched MALL) ----------------
// 128 blocks x 512 threads (8 waves). Blocks 0-63: layer 0; 64-127: layer 1
// (trailing one step). Block owns j-slice [j0,j0+16) of all 3 gates.
// SYNC: y0/y1 poisoned 0x7F at launch; consumer waves load their A-fragments
// agent-coherently and check against the sentinel (store IS the signal; each
// y u32 written exactly once; |h|<1 so 0x7F7F unreachable).
// THIS ROUND: the fragment fetch is 16 inline-asm global_load_dwordx4 sc0 sc1
// (MALL, agent-coherent) issued back-to-back + ONE s_waitcnt vmcnt(0) --
// replacing 32 __hip_atomic_loads whose conservative per-op waitcnt serialized
// the fetch into ~32 MALL round trips (~8us == the observed step period).

__global__ __launch_bounds__(512, 2)
void gru_fused(const unsigned short* __restrict__ wih0, const unsigned short* __restrict__ whh0,
               const float* __restrict__ b0,
               const unsigned short* __restrict__ wih1, const unsigned short* __restrict__ whh1,
               const float* __restrict__ b1,
               const unsigned short* __restrict__ xtm, const unsigned short* __restrict__ zerosB,
               unsigned short* __restrict__ y0, unsigned short* __restrict__ y1,
               float* __restrict__ hlast0, float* __restrict__ hlast1) {
  __shared__ __align__(16) float part[8 * 2 * 3 * 64 * 4];   // 48 KB [w][m][g][lane][reg]
  const int tid  = threadIdx.x;
  const int lane = tid & 63;
  const int w    = tid >> 6;          // 0..7
  const int r16  = lane & 15;
  const int q    = lane >> 4;
  const bool L1  = blockIdx.x >= 64;
  const int  j0  = (L1 ? (int)blockIdx.x - 64 : (int)blockIdx.x) * 16;
  const bool hiw = w >= 4;

  // per-wave operand plan
  const unsigned short* Wsrc;
  int wstride, kbase, ncha;
  if (!L1) {
    if (!hiw) { Wsrc = wih0; wstride = 512;  kbase = w * 128;       ncha = 4; }
    else      { Wsrc = whh0; wstride = 1024; kbase = (w - 4) * 256; ncha = 8; }
  } else {
    if (!hiw) { Wsrc = wih1; wstride = 1024; kbase = w * 256;       ncha = 8; }
    else      { Wsrc = whh1; wstride = 1024; kbase = (w - 4) * 256; ncha = 8; }
  }

  // B-frags -> registers, once
  bf16x8 bw[3][8];
#pragma unroll
  for (int g = 0; g < 3; ++g)
#pragma unroll
    for (int c = 0; c < 8; ++c)
      if (c < ncha)
        bw[g][c] = *(const bf16x8*)(Wsrc + (size_t)(g * H_ + j0 + r16) * wstride + kbase + c * 32 + q * 8);

  const float* bias = L1 ? b1 : b0;
  float br[2], bz[2], bn[2], phv[2] = {0.f, 0.f};
  if (tid < 256) {
    int jj = j0 + (tid & 7) * 2;
#pragma unroll
    for (int e = 0; e < 2; ++e) {
      br[e] = bias[jj + e]; bz[e] = bias[H_ + jj + e]; bn[e] = bias[2 * H_ + jj + e];
    }
  }

  unsigned short* ybuf  = L1 ? y1 : y0;
  float*          hlast = L1 ? hlast1 : hlast0;

  for (int t = 0; t < S_; ++t) {
    // ---- A-frags (self-synchronizing: poll data against sentinel) ----
    const unsigned short* Asrc;
    int astride; bool plainA;
    if (!hiw) {
      if (!L1) { Asrc = xtm + (size_t)t * B_ * 512; astride = 512;  plainA = true; }
      else     { Asrc = y0  + (size_t)t * B_ * H_;  astride = 1024; plainA = false; }
    } else {
      Asrc = t ? ybuf + (size_t)(t - 1) * B_ * H_ : zerosB; astride = 1024; plainA = (t == 0);
    }
    union AU { unsigned long long qq[2]; unsigned int dd[4]; u32x4 u4; bf16x8 v; };
    AU a0[8], a1[8];
    const unsigned short* ap0 = Asrc + (size_t)r16 * astride + kbase + q * 8;
    const unsigned short* ap1 = ap0 + 16 * astride;
    if (plainA) {
#pragma unroll
      for (int c = 0; c < 8; ++c) if (c < ncha) {
        a0[c].v = *(const bf16x8*)(ap0 + c * 32);
        a1[c].v = *(const bf16x8*)(ap1 + c * 32);
      }
    } else {
      // polled waves always have ncha==8. Batched agent-coherent fetch:
      // 16 loads in flight -> ONE waitcnt -> check. ~1 MALL RT per iteration.
      int spins = 0;
      for (;;) {
#pragma unroll
        for (int c = 0; c < 8; ++c) {
          ld4_mall(ap0 + c * 32, a0[c].u4);
          ld4_mall(ap1 + c * 32, a1[c].u4);
        }
        asm volatile("s_waitcnt vmcnt(0)"
          : "+v"(a0[0].u4), "+v"(a0[1].u4), "+v"(a0[2].u4), "+v"(a0[3].u4),
            "+v"(a0[4].u4), "+v"(a0[5].u4), "+v"(a0[6].u4), "+v"(a0[7].u4),
            "+v"(a1[0].u4), "+v"(a1[1].u4), "+v"(a1[2].u4), "+v"(a1[3].u4),
            "+v"(a1[4].u4), "+v"(a1[5].u4), "+v"(a1[6].u4), "+v"(a1[7].u4)
          :: "memory");
        __builtin_amdgcn_sched_barrier(0);
        int ok = 1;
#pragma unroll
        for (int c = 0; c < 8; ++c)
#pragma unroll
          for (int d = 0; d < 4; ++d)
            ok &= (a0[c].dd[d] != SENT32) & (a1[c].dd[d] != SENT32);
        if (__all(ok)) break;
        if (++spins > (1 << 20)) break;    // hang-safety only
        if (spins > 8) __builtin_amdgcn_s_sleep(1);
      }
    }

    f32x4 acc[2][3];
#pragma unroll
    for (int m = 0; m < 2; ++m)
#pragma unroll
      for (int g = 0; g < 3; ++g)
#pragma unroll
        for (int u = 0; u < 4; ++u) acc[m][g][u] = 0.f;

#pragma unroll
    for (int c = 0; c < 8; ++c) if (c < ncha)
#pragma unroll
      for (int g = 0; g < 3; ++g) {
        acc[0][g] = __builtin_amdgcn_mfma_f32_16x16x32_bf16(a0[c].v, bw[g][c], acc[0][g], 0, 0, 0);
        acc[1][g] = __builtin_amdgcn_mfma_f32_16x16x32_bf16(a1[c].v, bw[g][c], acc[1][g], 0, 0, 0);
      }

#pragma unroll
    for (int m = 0; m < 2; ++m)
#pragma unroll
      for (int g = 0; g < 3; ++g)
        *(f32x4*)&part[(((w * 2 + m) * 3 + g) * 64 + lane) * 4] = acc[m][g];
    __syncthreads();

    // ---- epilogue: 256 threads x 2 outputs; packed u32 store is the signal ----
    if (tid < 256) {
      unsigned short* yt = ybuf + (size_t)t * (B_ * H_);
      int b = tid >> 3, jp = (tid & 7) * 2;
      int m = b >> 4, q2 = (b >> 2) & 3, reg = b & 3;
      float hv2[2];
#pragma unroll
      for (int e = 0; e < 2; ++e) {
        int jj = jp + e;
        float hr = 0.f, hz = 0.f, nx = 0.f, nh = 0.f;
#pragma unroll
        for (int ww = 0; ww < 8; ++ww) {
          int base = (ww * 2 + m) * 3;
          float vr = part[((base + 0) * 64 + q2 * 16 + jj) * 4 + reg];
          float vz = part[((base + 1) * 64 + q2 * 16 + jj) * 4 + reg];
          float vn = part[((base + 2) * 64 + q2 * 16 + jj) * 4 + reg];
          hr += vr; hz += vz;
          if (ww < 4) nx += vn; else nh += vn;
        }
        float r  = __builtin_amdgcn_rcpf(1.f + __expf(-(hr + br[e])));
        float z  = __builtin_amdgcn_rcpf(1.f + __expf(-(hz + bz[e])));
        float a2 = nx + bn[e] + nh + r * nh;
        float nn = 1.f - 2.f * __builtin_amdgcn_rcpf(__expf(2.f * a2) + 1.f);  // tanh
        float hv = (1.f - z) * nn + z * phv[e];
        phv[e] = hv; hv2[e] = hv;
      }
      unsigned int pk = (unsigned int)f2bf(hv2[0]) | ((unsigned int)f2bf(hv2[1]) << 16);
      st_mall_b32(yt + (size_t)b * H_ + j0 + jp, pk);   // agent-coherent signal+data
      if (t == S_ - 1) {
        hlast[b * H_ + j0 + jp]     = hv2[0];
        hlast[b * H_ + j0 + jp + 1] = hv2[1];
      }
    }
    __syncthreads();   // drains vmcnt -> y stores committed before next step
  }
}

extern "C" void kernel_launch(void* const* d_in, const int* in_sizes, int n_in,
                              void* d_out, int out_size, void* d_ws, size_t ws_size,
                              hipStream_t stream) {
  const float* x    = (const float*)d_in[0];
  const float* Wih0 = (const float*)d_in[1];
  const float* Whh0 = (const float*)d_in[2];
  const float* b0   = (const float*)d_in[3];
  const float* Wih1 = (const float*)d_in[4];
  const float* Whh1 = (const float*)d_in[5];
  const float* b1   = (const float*)d_in[6];
  const float* Wlin = (const float*)d_in[7];
  const float* blin = (const float*)d_in[8];
  float* out = (float*)d_out;

  char* p = (char*)d_ws;
  size_t off = 0;
  auto alloc = [&](size_t bytes) { void* r = p + off; off += (bytes + 255) & ~(size_t)255; return r; };

  unsigned short* xtm   = (unsigned short*)alloc((size_t)8388608 * 2);   // (S,B,512) bf16
  unsigned short* wih0b = (unsigned short*)alloc((size_t)1572864 * 2);
  unsigned short* whh0b = (unsigned short*)alloc((size_t)3145728 * 2);
  unsigned short* wih1b = (unsigned short*)alloc((size_t)3145728 * 2);
  unsigned short* whh1b = (unsigned short*)alloc((size_t)3145728 * 2);
  unsigned short* wlinb = (unsigned short*)alloc((size_t)524288 * 2);
  unsigned short* y0b   = (unsigned short*)alloc((size_t)16777216 * 2);  // (S,B,H) bf16
  unsigned short* y1b   = (unsigned short*)alloc((size_t)16777216 * 2);
  unsigned short* zerosB= (unsigned short*)alloc((size_t)B_ * H_ * 2);

  // poison y buffers: 0x7F7F bf16 sentinel (unreachable since |h|<1)
  (void)hipMemsetAsync(y0b, 0x7F, (size_t)16777216 * 2, stream);
  (void)hipMemsetAsync(y1b, 0x7F, (size_t)16777216 * 2, stream);
  (void)hipMemsetAsync(zerosB, 0, (size_t)B_ * H_ * 2, stream);

  auto cast = [&](const float* in, unsigned short* o, int n) {
    cast_f32_bf16<<<n / 256, 256, 0, stream>>>(in, o, n);
  };
  cast_transpose_x<<<16384, 128, 0, stream>>>(x, xtm);
  cast(Wih0, wih0b, 1572864);
  cast(Whh0, whh0b, 3145728);
  cast(Wih1, wih1b, 3145728);
  cast(Whh1, whh1b, 3145728);
  cast(Wlin, wlinb, 524288);

  float* hlast0 = out + 8388608;
  float* hlast1 = out + 8388608 + B_ * H_;

  gru_fused<<<128, 512, 0, stream>>>(wih0b, whh0b, b0, wih1b, whh1b, b1,
                                     xtm, zerosB, y0b, y1b, hlast0, hlast1);

  // final: out = y1 @ Wlin^T + blin, C rows -> (b,s)
  {
    dim3 g(512 / 128, 16384 / 128);
    gemm_bf16<0, 1, float><<<g, 256, 0, stream>>>(y1b, wlinb, blin, out, 16384, 512, 1024);
  }
}